// Round 4
// baseline (759.428 us; speedup 1.0000x reference)
//
#include <hip/hip_runtime.h>

// Problem constants (B=2, S=2048, D_IN=2048, H=16, G=4, HD=128)
#define S_LEN 2048
#define NROWS 4096      // B*S
#define DIN   2048
#define DQKV  5120      // 4096 (q|gate) + 512 K + 512 V
#define DQG   4096

typedef __bf16 bf16x8 __attribute__((ext_vector_type(8)));
typedef float  floatx4 __attribute__((ext_vector_type(4)));
typedef unsigned short u16;

#define QK_SCALE 0.08838834764831845f   // 128^-0.5, folded into Q

__device__ __forceinline__ u16 f2bf(float f) {
  unsigned int u = __float_as_uint(f);
  u += 0x7fffu + ((u >> 16) & 1u);   // RNE
  return (u16)(u >> 16);
}
__device__ __forceinline__ float bf2f(u16 v) {
  return __uint_as_float(((unsigned int)v) << 16);
}
// XOR-8 chunk swizzle within each 64-element column group, keyed by row&7.
// Applied to GEMM-operand matrices only (baked into global layout so the
// position-preserving global_load_lds DMA lands it pre-swizzled in LDS).
__device__ __forceinline__ int swz(int col, int row) {
  return (col & ~63) | ((((col >> 3) & 7) ^ (row & 7)) << 3) | (col & 7);
}

__device__ __forceinline__ void gload_lds16(const void* g, void* l) {
  __builtin_amdgcn_global_load_lds(
      (__attribute__((address_space(1))) void*)(void*)(g),
      (__attribute__((address_space(3))) void*)(l), 16, 0, 0);
}

// ---------------- x fp32 -> bf16, swizzled (C = 2048) ----------------
__global__ __launch_bounds__(256) void cvt_x(const float* __restrict__ src,
                                             u16* __restrict__ dst) {
  const int i = blockIdx.x * 256 + threadIdx.x;   // one float4 per thread
  const int row = i >> 9, col = (i & 511) << 2;   // 512 float4 per row
  const float4 v = reinterpret_cast<const float4*>(src)[i];
  ushort4 o;
  o.x = f2bf(v.x); o.y = f2bf(v.y); o.z = f2bf(v.z); o.w = f2bf(v.w);
  *reinterpret_cast<ushort4*>(dst + (size_t)row * DIN + swz(col, row)) = o;
}

// ---------------- transpose + convert + swizzle: src[R][C] f32 -> dst[C][R] bf16 ----------------
__global__ __launch_bounds__(256) void tcvt(const float* __restrict__ src,
                                            u16* __restrict__ dst,
                                            int R, int C, int dld) {
  __shared__ float tile[32][33];
  const int c0 = blockIdx.x * 32, r0 = blockIdx.y * 32;
  const int t = threadIdx.x;
  {
    const int rl = t >> 3, cl4 = (t & 7) * 4;
    const float4 v = *reinterpret_cast<const float4*>(src + (size_t)(r0 + rl) * C + c0 + cl4);
    tile[rl][cl4 + 0] = v.x; tile[rl][cl4 + 1] = v.y;
    tile[rl][cl4 + 2] = v.z; tile[rl][cl4 + 3] = v.w;
  }
  __syncthreads();
  {
    const int cl = t >> 3, rl4 = (t & 7) * 4;
    ushort4 o;
    o.x = f2bf(tile[rl4 + 0][cl]); o.y = f2bf(tile[rl4 + 1][cl]);
    o.z = f2bf(tile[rl4 + 2][cl]); o.w = f2bf(tile[rl4 + 3][cl]);
    const int rd = c0 + cl, cd = r0 + rl4;      // dst (row, col)
    *reinterpret_cast<ushort4*>(dst + (size_t)rd * dld + swz(cd, rd)) = o;
  }
}

// ---------------- bf16 GEMM, BK=64: C[M][N] = A[M][K] @ Bt[N][K]^T ----------------
// A, Bt stored with swz() layout. C plain (fp32 or bf16).
template <bool BF16_OUT>
__global__ __launch_bounds__(256) void gemm_bt(const u16* __restrict__ A,
                                               const u16* __restrict__ Bt,
                                               void* __restrict__ Cv,
                                               int M, int N, int K) {
  __shared__ __align__(16) u16 As[128 * 64];
  __shared__ __align__(16) u16 Bs[128 * 64];
  const int tid = threadIdx.x, wv = tid >> 6, lane = tid & 63;
  const int m0 = blockIdx.y * 128, n0 = blockIdx.x * 128;
  const int wm = (wv >> 1) * 64, wn = (wv & 1) * 64;
  const int frow = lane & 15, quad = lane >> 4, fsw = frow & 7;
  const int srow = lane >> 3, scol = (lane & 7) * 8;
  floatx4 acc[4][4] = {};
  for (int k0 = 0; k0 < K; k0 += 64) {
#pragma unroll
    for (int i = 0; i < 4; ++i) {
      const int rr = (wv * 4 + i) * 8;
      gload_lds16(A  + (size_t)(m0 + rr + srow) * K + k0 + scol, &As[rr * 64]);
      gload_lds16(Bt + (size_t)(n0 + rr + srow) * K + k0 + scol, &Bs[rr * 64]);
    }
    __syncthreads();
#pragma unroll
    for (int ks = 0; ks < 2; ++ks) {
      bf16x8 af[4], bfr[4];
#pragma unroll
      for (int mi = 0; mi < 4; ++mi)
        af[mi] = *reinterpret_cast<const bf16x8*>(
            &As[(wm + mi * 16 + frow) * 64 + (((ks * 4 + quad) ^ fsw) << 3)]);
#pragma unroll
      for (int ni = 0; ni < 4; ++ni)
        bfr[ni] = *reinterpret_cast<const bf16x8*>(
            &Bs[(wn + ni * 16 + frow) * 64 + (((ks * 4 + quad) ^ fsw) << 3)]);
#pragma unroll
      for (int mi = 0; mi < 4; ++mi)
#pragma unroll
        for (int ni = 0; ni < 4; ++ni)
          acc[mi][ni] = __builtin_amdgcn_mfma_f32_16x16x32_bf16(af[mi], bfr[ni], acc[mi][ni], 0, 0, 0);
    }
    __syncthreads();
  }
  const int crow = (lane >> 4) * 4, ccol = lane & 15;
#pragma unroll
  for (int mi = 0; mi < 4; ++mi)
#pragma unroll
    for (int ni = 0; ni < 4; ++ni) {
      const size_t base = (size_t)(m0 + wm + mi * 16 + crow) * N + (n0 + wn + ni * 16 + ccol);
      if constexpr (BF16_OUT) {
        u16* C = (u16*)Cv;
#pragma unroll
        for (int r = 0; r < 4; ++r) C[base + (size_t)r * N] = f2bf(acc[mi][ni][r]);
      } else {
        float* C = (float*)Cv;
#pragma unroll
        for (int r = 0; r < 4; ++r) C[base + (size_t)r * N] = acc[mi][ni][r];
      }
    }
}

// ---------------- fused RMSNorm + RoPE for Q (scale folded in), bf16 in ----------------
__global__ __launch_bounds__(256) void qnorm_rope(const u16* __restrict__ QKV,
                                                  const float* __restrict__ w,
                                                  const float* __restrict__ cosT,
                                                  const float* __restrict__ sinT,
                                                  u16* __restrict__ Qb) {
  const int wv = threadIdx.x >> 6, lane = threadIdx.x & 63;
  const int idx = blockIdx.x * 4 + wv;      // row*16 + h
  const int h = idx & 15, row = idx >> 4;   // row = b*S + s
  const int s = row & (S_LEN - 1), b = row >> 11;
  const u16* base = QKV + (size_t)row * DQKV + h * 256;
  const float v0 = bf2f(base[lane]), v1 = bf2f(base[lane + 64]);
  float ss = v0 * v0 + v1 * v1;
#pragma unroll
  for (int m = 32; m >= 1; m >>= 1) ss += __shfl_xor(ss, m);
  const float rn = rsqrtf(ss * (1.0f / 128.0f) + 1e-6f) * QK_SCALE;
  const float n0 = v0 * rn * (1.0f + w[lane]);
  const float n1 = v1 * rn * (1.0f + w[lane + 64]);
  const float c0 = cosT[(size_t)s * 128 + lane], c1 = cosT[(size_t)s * 128 + lane + 64];
  const float sn0 = sinT[(size_t)s * 128 + lane], sn1 = sinT[(size_t)s * 128 + lane + 64];
  u16* qb = Qb + ((size_t)(b * 16 + h) * S_LEN + s) * 128;
  qb[lane]      = f2bf(n0 * c0 - n1 * sn0);
  qb[lane + 64] = f2bf(n1 * c1 + n0 * sn1);
}

// ---------------- fused RMSNorm + RoPE for K (plain layout) ----------------
__global__ __launch_bounds__(256) void knorm_rope(const u16* __restrict__ QKV,
                                                  const float* __restrict__ w,
                                                  const float* __restrict__ cosT,
                                                  const float* __restrict__ sinT,
                                                  u16* __restrict__ Kb) {
  const int wv = threadIdx.x >> 6, lane = threadIdx.x & 63;
  const int idx = blockIdx.x * 4 + wv;      // row*4 + g
  const int g = idx & 3, row = idx >> 2;
  const int s = row & (S_LEN - 1), b = row >> 11;
  const u16* base = QKV + (size_t)row * DQKV + DQG + g * 128;
  const float v0 = bf2f(base[lane]), v1 = bf2f(base[lane + 64]);
  float ss = v0 * v0 + v1 * v1;
#pragma unroll
  for (int m = 32; m >= 1; m >>= 1) ss += __shfl_xor(ss, m);
  const float rn = rsqrtf(ss * (1.0f / 128.0f) + 1e-6f);
  const float n0 = v0 * rn * (1.0f + w[lane]);
  const float n1 = v1 * rn * (1.0f + w[lane + 64]);
  const float c0 = cosT[(size_t)s * 128 + lane], c1 = cosT[(size_t)s * 128 + lane + 64];
  const float sn0 = sinT[(size_t)s * 128 + lane], sn1 = sinT[(size_t)s * 128 + lane + 64];
  u16* kb = Kb + ((size_t)(b * 4 + g) * S_LEN + s) * 128;
  kb[lane]      = f2bf(n0 * c0 - n1 * sn0);
  kb[lane + 64] = f2bf(n1 * c1 + n0 * sn1);
}

// ---------------- V: QKV bf16 cols 4608.. -> Vt bf16 [bg][d][s] (plain) ----------------
__global__ __launch_bounds__(256) void vtrans(const u16* __restrict__ QKV,
                                              u16* __restrict__ Vt) {
  __shared__ u16 tile[32][40];
  const int bg = blockIdx.z;                 // b*4+g
  const int s0 = blockIdx.x * 32, d0 = blockIdx.y * 32;
  const int b = bg >> 2, g = bg & 3;
  const int t = threadIdx.x;
  {
    const int sl = t >> 3, dl4 = (t & 7) * 4;
    const ushort4 v = *reinterpret_cast<const ushort4*>(
        QKV + (size_t)(b * S_LEN + s0 + sl) * DQKV + DQG + 512 + g * 128 + d0 + dl4);
    tile[sl][dl4 + 0] = v.x; tile[sl][dl4 + 1] = v.y;
    tile[sl][dl4 + 2] = v.z; tile[sl][dl4 + 3] = v.w;
  }
  __syncthreads();
  {
    const int dl = t >> 3, sl4 = (t & 7) * 4;
    ushort4 o;
    o.x = tile[sl4 + 0][dl]; o.y = tile[sl4 + 1][dl];
    o.z = tile[sl4 + 2][dl]; o.w = tile[sl4 + 3][dl];
    *reinterpret_cast<ushort4*>(Vt + (size_t)(bg * 128 + d0 + dl) * S_LEN + s0 + sl4) = o;
  }
}

// ---------------- barrier-free MFMA flash attention + gating ----------------
// grid (32 qtiles, B*H); block = 4 waves, wave w owns q rows [qt*64+w*16, +16).
// K/V fragments loaded directly from global (L2-resident); only LDS use is the
// wave-private P C->A layout roundtrip. NO __syncthreads anywhere.
__global__ __launch_bounds__(256, 3) void attn(const u16* __restrict__ Qb,
                                               const u16* __restrict__ Kb,
                                               const u16* __restrict__ Vt,
                                               const u16* __restrict__ QKV,
                                               u16* __restrict__ ctxg) {
  __shared__ __align__(16) u16 Ps[4][16 * 68]; // per-wave P [q][key], stride 68
  const int tid = threadIdx.x, wv = tid >> 6, lane = tid & 63;
  const int qt = blockIdx.x, bh = blockIdx.y;
  const int b = bh >> 4, h = bh & 15, g = h >> 2, bg = b * 4 + g;
  const int f = lane & 15, quad = lane >> 4, fq = quad * 8;
  const u16* Kp = Kb + (size_t)bg * S_LEN * 128;
  const u16* Vp = Vt + (size_t)bg * 128 * S_LEN;
  u16* Pw = Ps[wv];

  const u16* Qp = Qb + ((size_t)bh * S_LEN + qt * 64 + wv * 16) * 128;
  bf16x8 aq[4];
#pragma unroll
  for (int c = 0; c < 4; ++c)
    aq[c] = *reinterpret_cast<const bf16x8*>(&Qp[(size_t)f * 128 + c * 32 + fq]);

  floatx4 o[8] = {};
  float lsum[4] = {0.f, 0.f, 0.f, 0.f};
  const int nkt = qt + 1;

  for (int kt = 0; kt < nkt; ++kt) {
    const int k0 = kt * 64;
    // QK^T: K fragments straight from global (16 rows x 64B per frag-quad)
    floatx4 sc[4] = {};
#pragma unroll
    for (int c = 0; c < 4; ++c) {
      bf16x8 bk[4];
#pragma unroll
      for (int n = 0; n < 4; ++n)
        bk[n] = *reinterpret_cast<const bf16x8*>(
            &Kp[(size_t)(k0 + n * 16 + f) * 128 + c * 32 + fq]);
#pragma unroll
      for (int n = 0; n < 4; ++n)
        sc[n] = __builtin_amdgcn_mfma_f32_16x16x32_bf16(aq[c], bk[n], sc[n], 0, 0, 0);
    }

    // softmax without running max (scores bounded by sqrt(128))
    const int qrow0 = qt * 64 + wv * 16 + quad * 4;
#pragma unroll
    for (int n = 0; n < 4; ++n) {
      const int key = k0 + n * 16 + f;
#pragma unroll
      for (int r = 0; r < 4; ++r) {
        const float p = (key <= qrow0 + r) ? __expf(sc[n][r]) : 0.f;
        lsum[r] += p;
        Pw[(quad * 4 + r) * 68 + n * 16 + f] = f2bf(p);
      }
    }

    // P @ V, V fragments straight from global
#pragma unroll
    for (int kf = 0; kf < 2; ++kf) {
      bf16x8 pf = *reinterpret_cast<const bf16x8*>(&Pw[f * 68 + kf * 32 + fq]);
#pragma unroll
      for (int dt = 0; dt < 8; ++dt) {
        bf16x8 bv = *reinterpret_cast<const bf16x8*>(
            &Vp[(size_t)(dt * 16 + f) * S_LEN + k0 + kf * 32 + fq]);
        o[dt] = __builtin_amdgcn_mfma_f32_16x16x32_bf16(pf, bv, o[dt], 0, 0, 0);
      }
    }
  }

  // row sums: reduce lane-partials across the 16 f-lanes of each quad
#pragma unroll
  for (int r = 0; r < 4; ++r) {
#pragma unroll
    for (int mm = 8; mm >= 1; mm >>= 1) lsum[r] += __shfl_xor(lsum[r], mm);
  }

  // epilogue: 1/l, sigmoid gate (bf16), swizzled bf16 ctx write
#pragma unroll
  for (int r = 0; r < 4; ++r) {
    const int s = qt * 64 + wv * 16 + quad * 4 + r;
    const size_t grow = (size_t)b * S_LEN + s;
    const float inv = 1.0f / lsum[r];
#pragma unroll
    for (int dt = 0; dt < 8; ++dt) {
      const int d = dt * 16 + f;
      const float gate = bf2f(QKV[grow * DQKV + h * 256 + 128 + d]);
      const float val = o[dt][r] * inv * (1.0f / (1.0f + __expf(-gate)));
      const int col = h * 128 + d;
      ctxg[grow * 2048 + swz(col, (int)grow)] = f2bf(val);
    }
  }
}

extern "C" void kernel_launch(void* const* d_in, const int* in_sizes, int n_in,
                              void* d_out, int out_size, void* d_ws, size_t ws_size,
                              hipStream_t stream) {
  const float* x    = (const float*)d_in[0];
  const float* Wq   = (const float*)d_in[1];
  const float* Wk   = (const float*)d_in[2];
  const float* Wv   = (const float*)d_in[3];
  const float* Wo   = (const float*)d_in[4];
  const float* qnw  = (const float*)d_in[5];
  const float* knw  = (const float*)d_in[6];
  const float* cosT = (const float*)d_in[7];
  const float* sinT = (const float*)d_in[8];
  // d_in[9] = mask (unused; causality computed analytically)

  char* p = (char*)d_ws;
  u16*   xb    = (u16*)p;  p += (size_t)NROWS * DIN * 2;       // x bf16 (swizzled)
  u16*   WqkvT = (u16*)p;  p += (size_t)DQKV * DIN * 2;        // [Wq|Wk|Wv]^T (swizzled)
  u16*   WoT   = (u16*)p;  p += (size_t)2048 * 2048 * 2;       // Wo^T (swizzled)
  u16*   QKVb  = (u16*)p;  p += (size_t)NROWS * DQKV * 2;      // qkv proj bf16 (plain)
  u16*   Qbf   = (u16*)p;  p += (size_t)2 * 16 * S_LEN * 128 * 2;
  u16*   Kbf   = (u16*)p;  p += (size_t)2 * 4 * S_LEN * 128 * 2;
  u16*   Vtb   = (u16*)p;  p += (size_t)2 * 4 * S_LEN * 128 * 2;
  u16*   ctxg  = (u16*)p;  p += (size_t)NROWS * 2048 * 2;      // gated ctx (swizzled)

  cvt_x<<<8192, 256, 0, stream>>>(x, xb);
  tcvt<<<dim3(128, 64), 256, 0, stream>>>(Wq, WqkvT, 2048, 4096, 2048);
  tcvt<<<dim3(16, 64), 256, 0, stream>>>(Wk, WqkvT + (size_t)4096 * 2048, 2048, 512, 2048);
  tcvt<<<dim3(16, 64), 256, 0, stream>>>(Wv, WqkvT + (size_t)4608 * 2048, 2048, 512, 2048);
  tcvt<<<dim3(64, 64), 256, 0, stream>>>(Wo, WoT, 2048, 2048, 2048);

  gemm_bt<true><<<dim3(40, 32), 256, 0, stream>>>(xb, WqkvT, QKVb, NROWS, DQKV, DIN);

  qnorm_rope<<<16384, 256, 0, stream>>>(QKVb, qnw, cosT, sinT, Qbf);
  knorm_rope<<<4096, 256, 0, stream>>>(QKVb, knw, cosT, sinT, Kbf);
  vtrans<<<dim3(64, 4, 8), 256, 0, stream>>>(QKVb, Vtb);

  attn<<<dim3(32, 32), 256, 0, stream>>>(Qbf, Kbf, Vtb, QKVb, ctxg);

  gemm_bt<false><<<dim3(16, 32), 256, 0, stream>>>(ctxg, WoT, (float*)d_out, NROWS, 2048, 2048);
}

// Round 5
// 496.410 us; speedup vs baseline: 1.5298x; 1.5298x over previous
//
#include <hip/hip_runtime.h>

// Problem constants (B=2, S=2048, D_IN=2048, H=16, G=4, HD=128)
#define S_LEN 2048
#define NROWS 4096      // B*S
#define DIN   2048
#define DQKV  5120      // 4096 (q|gate) + 512 K + 512 V
#define DQG   4096

typedef __bf16 bf16x8 __attribute__((ext_vector_type(8)));
typedef float  floatx4 __attribute__((ext_vector_type(4)));
typedef unsigned short u16;

// 128^-0.5 * log2(e): folded into Q so softmax uses exp2 (native v_exp_f32)
#define QK_SCALE (0.08838834764831845f * 1.4426950408889634f)

__device__ __forceinline__ u16 f2bf(float f) {
  unsigned int u = __float_as_uint(f);
  u += 0x7fffu + ((u >> 16) & 1u);   // RNE
  return (u16)(u >> 16);
}
__device__ __forceinline__ float bf2f(u16 v) {
  return __uint_as_float(((unsigned int)v) << 16);
}
// XOR-8 chunk swizzle within each 64-element column group, keyed by row&7.
// Applied to GEMM-operand matrices (baked into global layout so the
// position-preserving global_load_lds DMA lands it pre-swizzled in LDS).
__device__ __forceinline__ int swz(int col, int row) {
  return (col & ~63) | ((((col >> 3) & 7) ^ (row & 7)) << 3) | (col & 7);
}

__device__ __forceinline__ void gload_lds16(const void* g, void* l) {
  __builtin_amdgcn_global_load_lds(
      (__attribute__((address_space(1))) void*)(void*)(g),
      (__attribute__((address_space(3))) void*)(l), 16, 0, 0);
}

// ---------------- x fp32 -> bf16, swizzled (C = 2048) ----------------
__global__ __launch_bounds__(256) void cvt_x(const float* __restrict__ src,
                                             u16* __restrict__ dst) {
  const int i = blockIdx.x * 256 + threadIdx.x;   // one float4 per thread
  const int row = i >> 9, col = (i & 511) << 2;   // 512 float4 per row
  const float4 v = reinterpret_cast<const float4*>(src)[i];
  ushort4 o;
  o.x = f2bf(v.x); o.y = f2bf(v.y); o.z = f2bf(v.z); o.w = f2bf(v.w);
  *reinterpret_cast<ushort4*>(dst + (size_t)row * DIN + swz(col, row)) = o;
}

// ---------------- transpose + convert + swizzle: src[R][C] f32 -> dst[C][R] bf16 ----------------
__global__ __launch_bounds__(256) void tcvt(const float* __restrict__ src,
                                            u16* __restrict__ dst,
                                            int R, int C, int dld) {
  __shared__ float tile[32][33];
  const int c0 = blockIdx.x * 32, r0 = blockIdx.y * 32;
  const int t = threadIdx.x;
  {
    const int rl = t >> 3, cl4 = (t & 7) * 4;
    const float4 v = *reinterpret_cast<const float4*>(src + (size_t)(r0 + rl) * C + c0 + cl4);
    tile[rl][cl4 + 0] = v.x; tile[rl][cl4 + 1] = v.y;
    tile[rl][cl4 + 2] = v.z; tile[rl][cl4 + 3] = v.w;
  }
  __syncthreads();
  {
    const int cl = t >> 3, rl4 = (t & 7) * 4;
    ushort4 o;
    o.x = f2bf(tile[rl4 + 0][cl]); o.y = f2bf(tile[rl4 + 1][cl]);
    o.z = f2bf(tile[rl4 + 2][cl]); o.w = f2bf(tile[rl4 + 3][cl]);
    const int rd = c0 + cl, cd = r0 + rl4;      // dst (row, col)
    *reinterpret_cast<ushort4*>(dst + (size_t)rd * dld + swz(cd, rd)) = o;
  }
}

// ---------------- bf16 GEMM, BK=64: C[M][N] = A[M][K] @ Bt[N][K]^T ----------------
// A, Bt stored with swz() layout. C plain (fp32 or bf16).
template <bool BF16_OUT>
__global__ __launch_bounds__(256) void gemm_bt(const u16* __restrict__ A,
                                               const u16* __restrict__ Bt,
                                               void* __restrict__ Cv,
                                               int M, int N, int K) {
  __shared__ __align__(16) u16 As[128 * 64];
  __shared__ __align__(16) u16 Bs[128 * 64];
  const int tid = threadIdx.x, wv = tid >> 6, lane = tid & 63;
  const int m0 = blockIdx.y * 128, n0 = blockIdx.x * 128;
  const int wm = (wv >> 1) * 64, wn = (wv & 1) * 64;
  const int frow = lane & 15, quad = lane >> 4, fsw = frow & 7;
  const int srow = lane >> 3, scol = (lane & 7) * 8;
  floatx4 acc[4][4] = {};
  for (int k0 = 0; k0 < K; k0 += 64) {
#pragma unroll
    for (int i = 0; i < 4; ++i) {
      const int rr = (wv * 4 + i) * 8;
      gload_lds16(A  + (size_t)(m0 + rr + srow) * K + k0 + scol, &As[rr * 64]);
      gload_lds16(Bt + (size_t)(n0 + rr + srow) * K + k0 + scol, &Bs[rr * 64]);
    }
    __syncthreads();
#pragma unroll
    for (int ks = 0; ks < 2; ++ks) {
      bf16x8 af[4], bfr[4];
#pragma unroll
      for (int mi = 0; mi < 4; ++mi)
        af[mi] = *reinterpret_cast<const bf16x8*>(
            &As[(wm + mi * 16 + frow) * 64 + (((ks * 4 + quad) ^ fsw) << 3)]);
#pragma unroll
      for (int ni = 0; ni < 4; ++ni)
        bfr[ni] = *reinterpret_cast<const bf16x8*>(
            &Bs[(wn + ni * 16 + frow) * 64 + (((ks * 4 + quad) ^ fsw) << 3)]);
#pragma unroll
      for (int mi = 0; mi < 4; ++mi)
#pragma unroll
        for (int ni = 0; ni < 4; ++ni)
          acc[mi][ni] = __builtin_amdgcn_mfma_f32_16x16x32_bf16(af[mi], bfr[ni], acc[mi][ni], 0, 0, 0);
    }
    __syncthreads();
  }
  const int crow = (lane >> 4) * 4, ccol = lane & 15;
#pragma unroll
  for (int mi = 0; mi < 4; ++mi)
#pragma unroll
    for (int ni = 0; ni < 4; ++ni) {
      const size_t base = (size_t)(m0 + wm + mi * 16 + crow) * N + (n0 + wn + ni * 16 + ccol);
      if constexpr (BF16_OUT) {
        u16* C = (u16*)Cv;
#pragma unroll
        for (int r = 0; r < 4; ++r) C[base + (size_t)r * N] = f2bf(acc[mi][ni][r]);
      } else {
        float* C = (float*)Cv;
#pragma unroll
        for (int r = 0; r < 4; ++r) C[base + (size_t)r * N] = acc[mi][ni][r];
      }
    }
}

// ---------------- fused RMSNorm + RoPE for Q (scale folded in), bf16 in ----------------
__global__ __launch_bounds__(256) void qnorm_rope(const u16* __restrict__ QKV,
                                                  const float* __restrict__ w,
                                                  const float* __restrict__ cosT,
                                                  const float* __restrict__ sinT,
                                                  u16* __restrict__ Qb) {
  const int wv = threadIdx.x >> 6, lane = threadIdx.x & 63;
  const int idx = blockIdx.x * 4 + wv;      // row*16 + h
  const int h = idx & 15, row = idx >> 4;   // row = b*S + s
  const int s = row & (S_LEN - 1), b = row >> 11;
  const u16* base = QKV + (size_t)row * DQKV + h * 256;
  const float v0 = bf2f(base[lane]), v1 = bf2f(base[lane + 64]);
  float ss = v0 * v0 + v1 * v1;
#pragma unroll
  for (int m = 32; m >= 1; m >>= 1) ss += __shfl_xor(ss, m);
  const float rn = rsqrtf(ss * (1.0f / 128.0f) + 1e-6f) * QK_SCALE;
  const float n0 = v0 * rn * (1.0f + w[lane]);
  const float n1 = v1 * rn * (1.0f + w[lane + 64]);
  const float c0 = cosT[(size_t)s * 128 + lane], c1 = cosT[(size_t)s * 128 + lane + 64];
  const float sn0 = sinT[(size_t)s * 128 + lane], sn1 = sinT[(size_t)s * 128 + lane + 64];
  u16* qb = Qb + ((size_t)(b * 16 + h) * S_LEN + s) * 128;
  qb[lane]      = f2bf(n0 * c0 - n1 * sn0);
  qb[lane + 64] = f2bf(n1 * c1 + n0 * sn1);
}

// MFMA-fragment-packed index for K: element (key s, dim d) of one (b,g) slab.
// Fragment = 16 keys x 32 dims, stored as 64 lanes x 8 contiguous elements.
__device__ __forceinline__ int kpk_idx(int s, int d) {
  return ((s >> 4) << 11) + ((d >> 5) << 9) + ((s & 15) << 5) + (((d >> 3) & 3) << 3) + (d & 7);
}

// ---------------- fused RMSNorm + RoPE for K -> fragment-packed layout ----------------
__global__ __launch_bounds__(256) void knorm_rope(const u16* __restrict__ QKV,
                                                  const float* __restrict__ w,
                                                  const float* __restrict__ cosT,
                                                  const float* __restrict__ sinT,
                                                  u16* __restrict__ Kpk) {
  const int wv = threadIdx.x >> 6, lane = threadIdx.x & 63;
  const int idx = blockIdx.x * 4 + wv;      // row*4 + g
  const int g = idx & 3, row = idx >> 2;
  const int s = row & (S_LEN - 1), b = row >> 11;
  const u16* base = QKV + (size_t)row * DQKV + DQG + g * 128;
  const float v0 = bf2f(base[lane]), v1 = bf2f(base[lane + 64]);
  float ss = v0 * v0 + v1 * v1;
#pragma unroll
  for (int m = 32; m >= 1; m >>= 1) ss += __shfl_xor(ss, m);
  const float rn = rsqrtf(ss * (1.0f / 128.0f) + 1e-6f);
  const float n0 = v0 * rn * (1.0f + w[lane]);
  const float n1 = v1 * rn * (1.0f + w[lane + 64]);
  const float c0 = cosT[(size_t)s * 128 + lane], c1 = cosT[(size_t)s * 128 + lane + 64];
  const float sn0 = sinT[(size_t)s * 128 + lane], sn1 = sinT[(size_t)s * 128 + lane + 64];
  u16* kb = Kpk + (size_t)(b * 4 + g) * (S_LEN * 128);
  kb[kpk_idx(s, lane)]      = f2bf(n0 * c0 - n1 * sn0);
  kb[kpk_idx(s, lane + 64)] = f2bf(n1 * c1 + n0 * sn1);
}

// ---------------- V: QKV bf16 cols 4608.. -> fragment-packed Vpk ----------------
// Fragment = 32 keys x 16 dims (B operand of PV): element (d, key s):
// idx = (s>>5)*4096 + (d>>4)*512 + (d&15)*32 + ((s>>3)&3)*8 + (s&7)
__global__ __launch_bounds__(256) void vtrans(const u16* __restrict__ QKV,
                                              u16* __restrict__ Vpk) {
  __shared__ u16 tile[32][40];
  const int bg = blockIdx.z;                 // b*4+g
  const int s0 = blockIdx.x * 32, d0 = blockIdx.y * 32;
  const int b = bg >> 2, g = bg & 3;
  const int t = threadIdx.x;
  {
    const int sl = t >> 3, dl4 = (t & 7) * 4;
    const ushort4 v = *reinterpret_cast<const ushort4*>(
        QKV + (size_t)(b * S_LEN + s0 + sl) * DQKV + DQG + 512 + g * 128 + d0 + dl4);
    tile[sl][dl4 + 0] = v.x; tile[sl][dl4 + 1] = v.y;
    tile[sl][dl4 + 2] = v.z; tile[sl][dl4 + 3] = v.w;
  }
  __syncthreads();
  {
    const int dl = t >> 3, sl4 = (t & 7) * 4;
    ushort4 o;
    o.x = tile[sl4 + 0][dl]; o.y = tile[sl4 + 1][dl];
    o.z = tile[sl4 + 2][dl]; o.w = tile[sl4 + 3][dl];
    const int d = d0 + dl, s = s0 + sl4;
    const int idx = ((s >> 5) << 12) + ((d >> 4) << 9) + ((d & 15) << 5) +
                    (((s >> 3) & 3) << 3) + (s & 7);
    *reinterpret_cast<ushort4*>(Vpk + (size_t)bg * (S_LEN * 128) + idx) = o;
  }
}

// ---------------- barrier-free MFMA flash attention + gating ----------------
// grid (8, B*H); block = 512 threads = 8 waves. Block handles 256-row q-tiles
// p and 7-p (two passes) -> uniform 40 k-tiles/block. Wave w owns 32 q rows.
// K/V fragments are 1KB-contiguous coalesced loads from the packed layouts
// (L2-resident). Only LDS: wave-private P roundtrip. NO __syncthreads.
__global__ __launch_bounds__(512, 2) void attn(const u16* __restrict__ Qb,
                                               const u16* __restrict__ Kpk,
                                               const u16* __restrict__ Vpk,
                                               const u16* __restrict__ QKV,
                                               u16* __restrict__ ctxg) {
  __shared__ __align__(16) u16 Ps[8][32 * 68]; // per-wave P [q][key], stride 68
  const int tid = threadIdx.x, wv = tid >> 6, lane = tid & 63;
  const int pp = blockIdx.x, bh = blockIdx.y;
  const int b = bh >> 4, h = bh & 15, g = h >> 2, bg = b * 4 + g;
  const int f = lane & 15, quad = lane >> 4, fq = quad * 8;
  const int lfrag = f * 32 + fq;               // lane offset inside a 512-elem fragment
  const u16* Kp = Kpk + (size_t)bg * (S_LEN * 128);
  const u16* Vp = Vpk + (size_t)bg * (S_LEN * 128);
  u16* Pw = Ps[wv];

  for (int pass = 0; pass < 2; ++pass) {
    const int qt = pass ? 7 - pp : pp;
    const int qbase = qt * 256 + wv * 32;
    bf16x8 aq[2][4];
#pragma unroll
    for (int qi = 0; qi < 2; ++qi) {
      const u16* Qp = Qb + ((size_t)bh * S_LEN + qbase + qi * 16) * 128;
#pragma unroll
      for (int c = 0; c < 4; ++c)
        aq[qi][c] = *reinterpret_cast<const bf16x8*>(&Qp[(size_t)f * 128 + c * 32 + fq]);
    }

    floatx4 o[2][8] = {};
    float lsum[2][4] = {};
    const int nkt = qt * 4 + 4;

    for (int kt = 0; kt < nkt; ++kt) {
      const int k0 = kt * 64;
      // ---- QK^T over 4 16-key fragments ----
#pragma unroll
      for (int n = 0; n < 4; ++n) {
        const u16* kfrag = Kp + (size_t)((k0 >> 4) + n) * 2048;
        floatx4 sc0 = {}, sc1 = {};
#pragma unroll
        for (int c = 0; c < 4; ++c) {
          bf16x8 bk = *reinterpret_cast<const bf16x8*>(&kfrag[c * 512 + lfrag]);
          sc0 = __builtin_amdgcn_mfma_f32_16x16x32_bf16(aq[0][c], bk, sc0, 0, 0, 0);
          sc1 = __builtin_amdgcn_mfma_f32_16x16x32_bf16(aq[1][c], bk, sc1, 0, 0, 0);
        }
        const int key = k0 + n * 16 + f;
#pragma unroll
        for (int qi = 0; qi < 2; ++qi) {
          const int qrow0 = qbase + qi * 16 + quad * 4;
          const floatx4 sc = qi ? sc1 : sc0;
#pragma unroll
          for (int r = 0; r < 4; ++r) {
            const float p = (key <= qrow0 + r) ? exp2f(sc[r]) : 0.f;
            lsum[qi][r] += p;
            Pw[(qi * 16 + quad * 4 + r) * 68 + n * 16 + f] = f2bf(p);
          }
        }
      }
      // ---- P @ V over 2 32-key fragments ----
#pragma unroll
      for (int kf = 0; kf < 2; ++kf) {
        const u16* vfrag = Vp + (size_t)((k0 >> 5) + kf) * 4096;
        bf16x8 pf0 = *reinterpret_cast<const bf16x8*>(&Pw[f * 68 + kf * 32 + fq]);
        bf16x8 pf1 = *reinterpret_cast<const bf16x8*>(&Pw[(16 + f) * 68 + kf * 32 + fq]);
#pragma unroll
        for (int dt = 0; dt < 8; ++dt) {
          bf16x8 bv = *reinterpret_cast<const bf16x8*>(&vfrag[dt * 512 + lfrag]);
          o[0][dt] = __builtin_amdgcn_mfma_f32_16x16x32_bf16(pf0, bv, o[0][dt], 0, 0, 0);
          o[1][dt] = __builtin_amdgcn_mfma_f32_16x16x32_bf16(pf1, bv, o[1][dt], 0, 0, 0);
        }
      }
    }

    // reduce lane-partial row sums across the 16 f-lanes of each quad
#pragma unroll
    for (int qi = 0; qi < 2; ++qi)
#pragma unroll
      for (int r = 0; r < 4; ++r) {
#pragma unroll
        for (int mm = 8; mm >= 1; mm >>= 1) lsum[qi][r] += __shfl_xor(lsum[qi][r], mm);
      }

    // epilogue: 1/l, sigmoid gate (bf16), swizzled bf16 ctx write
#pragma unroll
    for (int qi = 0; qi < 2; ++qi)
#pragma unroll
      for (int r = 0; r < 4; ++r) {
        const int s = qbase + qi * 16 + quad * 4 + r;
        const size_t grow = (size_t)b * S_LEN + s;
        const float inv = 1.0f / lsum[qi][r];
#pragma unroll
        for (int dt = 0; dt < 8; ++dt) {
          const int d = dt * 16 + f;
          const float gate = bf2f(QKV[grow * DQKV + h * 256 + 128 + d]);
          const float val = o[qi][dt][r] * inv * (1.0f / (1.0f + __expf(-gate)));
          const int col = h * 128 + d;
          ctxg[grow * 2048 + swz(col, (int)grow)] = f2bf(val);
        }
      }
  }
}

extern "C" void kernel_launch(void* const* d_in, const int* in_sizes, int n_in,
                              void* d_out, int out_size, void* d_ws, size_t ws_size,
                              hipStream_t stream) {
  const float* x    = (const float*)d_in[0];
  const float* Wq   = (const float*)d_in[1];
  const float* Wk   = (const float*)d_in[2];
  const float* Wv   = (const float*)d_in[3];
  const float* Wo   = (const float*)d_in[4];
  const float* qnw  = (const float*)d_in[5];
  const float* knw  = (const float*)d_in[6];
  const float* cosT = (const float*)d_in[7];
  const float* sinT = (const float*)d_in[8];
  // d_in[9] = mask (unused; causality computed analytically)

  char* p = (char*)d_ws;
  u16*   xb    = (u16*)p;  p += (size_t)NROWS * DIN * 2;       // x bf16 (swizzled)
  u16*   WqkvT = (u16*)p;  p += (size_t)DQKV * DIN * 2;        // [Wq|Wk|Wv]^T (swizzled)
  u16*   WoT   = (u16*)p;  p += (size_t)2048 * 2048 * 2;       // Wo^T (swizzled)
  u16*   QKVb  = (u16*)p;  p += (size_t)NROWS * DQKV * 2;      // qkv proj bf16 (plain)
  u16*   Qbf   = (u16*)p;  p += (size_t)2 * 16 * S_LEN * 128 * 2;
  u16*   Kpk   = (u16*)p;  p += (size_t)2 * 4 * S_LEN * 128 * 2;   // fragment-packed K
  u16*   Vpk   = (u16*)p;  p += (size_t)2 * 4 * S_LEN * 128 * 2;   // fragment-packed V
  u16*   ctxg  = (u16*)p;  p += (size_t)NROWS * 2048 * 2;      // gated ctx (swizzled)

  cvt_x<<<8192, 256, 0, stream>>>(x, xb);
  tcvt<<<dim3(128, 64), 256, 0, stream>>>(Wq, WqkvT, 2048, 4096, 2048);
  tcvt<<<dim3(16, 64), 256, 0, stream>>>(Wk, WqkvT + (size_t)4096 * 2048, 2048, 512, 2048);
  tcvt<<<dim3(16, 64), 256, 0, stream>>>(Wv, WqkvT + (size_t)4608 * 2048, 2048, 512, 2048);
  tcvt<<<dim3(64, 64), 256, 0, stream>>>(Wo, WoT, 2048, 2048, 2048);

  gemm_bt<true><<<dim3(40, 32), 256, 0, stream>>>(xb, WqkvT, QKVb, NROWS, DQKV, DIN);

  qnorm_rope<<<16384, 256, 0, stream>>>(QKVb, qnw, cosT, sinT, Qbf);
  knorm_rope<<<4096, 256, 0, stream>>>(QKVb, knw, cosT, sinT, Kpk);
  vtrans<<<dim3(64, 4, 8), 256, 0, stream>>>(QKVb, Vpk);

  attn<<<dim3(8, 32), 512, 0, stream>>>(Qbf, Kpk, Vpk, QKVb, ctxg);

  gemm_bt<false><<<dim3(16, 32), 256, 0, stream>>>(ctxg, WoT, (float*)d_out, NROWS, 2048, 2048);
}

// Round 6
// 406.647 us; speedup vs baseline: 1.8675x; 1.2207x over previous
//
#include <hip/hip_runtime.h>

// Problem constants (B=2, S=2048, D_IN=2048, H=16, G=4, HD=128)
#define S_LEN 2048
#define NROWS 4096      // B*S
#define DIN   2048
#define DQKV  5120      // 4096 (q|gate) + 512 K + 512 V
#define DQG   4096

typedef __bf16 bf16x8 __attribute__((ext_vector_type(8)));
typedef float  floatx4 __attribute__((ext_vector_type(4)));
typedef unsigned short u16;

// 128^-0.5 * log2(e): folded into Q so softmax uses exp2 (native v_exp_f32)
#define QK_SCALE (0.08838834764831845f * 1.4426950408889634f)

__device__ __forceinline__ u16 f2bf(float f) {
  unsigned int u = __float_as_uint(f);
  u += 0x7fffu + ((u >> 16) & 1u);   // RNE
  return (u16)(u >> 16);
}
__device__ __forceinline__ float bf2f(u16 v) {
  return __uint_as_float(((unsigned int)v) << 16);
}
// XOR-8 chunk swizzle within each 64-element column group, keyed by row&7.
// Applied to GEMM-operand matrices (baked into global layout so the
// position-preserving global_load_lds DMA lands it pre-swizzled in LDS).
__device__ __forceinline__ int swz(int col, int row) {
  return (col & ~63) | ((((col >> 3) & 7) ^ (row & 7)) << 3) | (col & 7);
}

__device__ __forceinline__ void gload_lds16(const void* g, void* l) {
  __builtin_amdgcn_global_load_lds(
      (__attribute__((address_space(1))) void*)(void*)(g),
      (__attribute__((address_space(3))) void*)(l), 16, 0, 0);
}

// ---------------- x fp32 -> bf16, swizzled (C = 2048) ----------------
__global__ __launch_bounds__(256) void cvt_x(const float* __restrict__ src,
                                             u16* __restrict__ dst) {
  const int i = blockIdx.x * 256 + threadIdx.x;   // one float4 per thread
  const int row = i >> 9, col = (i & 511) << 2;   // 512 float4 per row
  const float4 v = reinterpret_cast<const float4*>(src)[i];
  ushort4 o;
  o.x = f2bf(v.x); o.y = f2bf(v.y); o.z = f2bf(v.z); o.w = f2bf(v.w);
  *reinterpret_cast<ushort4*>(dst + (size_t)row * DIN + swz(col, row)) = o;
}

// ---------------- transpose + convert + swizzle: src[R][C] f32 -> dst[C][R] bf16 ----------------
__global__ __launch_bounds__(256) void tcvt(const float* __restrict__ src,
                                            u16* __restrict__ dst,
                                            int R, int C, int dld) {
  __shared__ float tile[32][33];
  const int c0 = blockIdx.x * 32, r0 = blockIdx.y * 32;
  const int t = threadIdx.x;
  {
    const int rl = t >> 3, cl4 = (t & 7) * 4;
    const float4 v = *reinterpret_cast<const float4*>(src + (size_t)(r0 + rl) * C + c0 + cl4);
    tile[rl][cl4 + 0] = v.x; tile[rl][cl4 + 1] = v.y;
    tile[rl][cl4 + 2] = v.z; tile[rl][cl4 + 3] = v.w;
  }
  __syncthreads();
  {
    const int cl = t >> 3, rl4 = (t & 7) * 4;
    ushort4 o;
    o.x = f2bf(tile[rl4 + 0][cl]); o.y = f2bf(tile[rl4 + 1][cl]);
    o.z = f2bf(tile[rl4 + 2][cl]); o.w = f2bf(tile[rl4 + 3][cl]);
    const int rd = c0 + cl, cd = r0 + rl4;      // dst (row, col)
    *reinterpret_cast<ushort4*>(dst + (size_t)rd * dld + swz(cd, rd)) = o;
  }
}

// ---------------- bf16 GEMM, BK=64: C[M][N] = A[M][K] @ Bt[N][K]^T ----------------
template <bool BF16_OUT>
__global__ __launch_bounds__(256) void gemm_bt(const u16* __restrict__ A,
                                               const u16* __restrict__ Bt,
                                               void* __restrict__ Cv,
                                               int M, int N, int K) {
  __shared__ __align__(16) u16 As[128 * 64];
  __shared__ __align__(16) u16 Bs[128 * 64];
  const int tid = threadIdx.x, wv = tid >> 6, lane = tid & 63;
  const int m0 = blockIdx.y * 128, n0 = blockIdx.x * 128;
  const int wm = (wv >> 1) * 64, wn = (wv & 1) * 64;
  const int frow = lane & 15, quad = lane >> 4, fsw = frow & 7;
  const int srow = lane >> 3, scol = (lane & 7) * 8;
  floatx4 acc[4][4] = {};
  for (int k0 = 0; k0 < K; k0 += 64) {
#pragma unroll
    for (int i = 0; i < 4; ++i) {
      const int rr = (wv * 4 + i) * 8;
      gload_lds16(A  + (size_t)(m0 + rr + srow) * K + k0 + scol, &As[rr * 64]);
      gload_lds16(Bt + (size_t)(n0 + rr + srow) * K + k0 + scol, &Bs[rr * 64]);
    }
    __syncthreads();
#pragma unroll
    for (int ks = 0; ks < 2; ++ks) {
      bf16x8 af[4], bfr[4];
#pragma unroll
      for (int mi = 0; mi < 4; ++mi)
        af[mi] = *reinterpret_cast<const bf16x8*>(
            &As[(wm + mi * 16 + frow) * 64 + (((ks * 4 + quad) ^ fsw) << 3)]);
#pragma unroll
      for (int ni = 0; ni < 4; ++ni)
        bfr[ni] = *reinterpret_cast<const bf16x8*>(
            &Bs[(wn + ni * 16 + frow) * 64 + (((ks * 4 + quad) ^ fsw) << 3)]);
#pragma unroll
      for (int mi = 0; mi < 4; ++mi)
#pragma unroll
        for (int ni = 0; ni < 4; ++ni)
          acc[mi][ni] = __builtin_amdgcn_mfma_f32_16x16x32_bf16(af[mi], bfr[ni], acc[mi][ni], 0, 0, 0);
    }
    __syncthreads();
  }
  const int crow = (lane >> 4) * 4, ccol = lane & 15;
#pragma unroll
  for (int mi = 0; mi < 4; ++mi)
#pragma unroll
    for (int ni = 0; ni < 4; ++ni) {
      const size_t base = (size_t)(m0 + wm + mi * 16 + crow) * N + (n0 + wn + ni * 16 + ccol);
      if constexpr (BF16_OUT) {
        u16* C = (u16*)Cv;
#pragma unroll
        for (int r = 0; r < 4; ++r) C[base + (size_t)r * N] = f2bf(acc[mi][ni][r]);
      } else {
        float* C = (float*)Cv;
#pragma unroll
        for (int r = 0; r < 4; ++r) C[base + (size_t)r * N] = acc[mi][ni][r];
      }
    }
}

// ---------------- fused RMSNorm + RoPE for Q (scale folded in), bf16 in ----------------
__global__ __launch_bounds__(256) void qnorm_rope(const u16* __restrict__ QKV,
                                                  const float* __restrict__ w,
                                                  const float* __restrict__ cosT,
                                                  const float* __restrict__ sinT,
                                                  u16* __restrict__ Qb) {
  const int wv = threadIdx.x >> 6, lane = threadIdx.x & 63;
  const int idx = blockIdx.x * 4 + wv;      // row*16 + h
  const int h = idx & 15, row = idx >> 4;   // row = b*S + s
  const int s = row & (S_LEN - 1), b = row >> 11;
  const u16* base = QKV + (size_t)row * DQKV + h * 256;
  const float v0 = bf2f(base[lane]), v1 = bf2f(base[lane + 64]);
  float ss = v0 * v0 + v1 * v1;
#pragma unroll
  for (int m = 32; m >= 1; m >>= 1) ss += __shfl_xor(ss, m);
  const float rn = rsqrtf(ss * (1.0f / 128.0f) + 1e-6f) * QK_SCALE;
  const float n0 = v0 * rn * (1.0f + w[lane]);
  const float n1 = v1 * rn * (1.0f + w[lane + 64]);
  const float c0 = cosT[(size_t)s * 128 + lane], c1 = cosT[(size_t)s * 128 + lane + 64];
  const float sn0 = sinT[(size_t)s * 128 + lane], sn1 = sinT[(size_t)s * 128 + lane + 64];
  u16* qb = Qb + ((size_t)(b * 16 + h) * S_LEN + s) * 128;
  qb[lane]      = f2bf(n0 * c0 - n1 * sn0);
  qb[lane + 64] = f2bf(n1 * c1 + n0 * sn1);
}

// MFMA-fragment-packed index for K: element (key s, dim d) of one (b,g) slab.
__device__ __forceinline__ int kpk_idx(int s, int d) {
  return ((s >> 4) << 11) + ((d >> 5) << 9) + ((s & 15) << 5) + (((d >> 3) & 3) << 3) + (d & 7);
}

// ---------------- fused RMSNorm + RoPE for K -> fragment-packed layout ----------------
__global__ __launch_bounds__(256) void knorm_rope(const u16* __restrict__ QKV,
                                                  const float* __restrict__ w,
                                                  const float* __restrict__ cosT,
                                                  const float* __restrict__ sinT,
                                                  u16* __restrict__ Kpk) {
  const int wv = threadIdx.x >> 6, lane = threadIdx.x & 63;
  const int idx = blockIdx.x * 4 + wv;      // row*4 + g
  const int g = idx & 3, row = idx >> 2;
  const int s = row & (S_LEN - 1), b = row >> 11;
  const u16* base = QKV + (size_t)row * DQKV + DQG + g * 128;
  const float v0 = bf2f(base[lane]), v1 = bf2f(base[lane + 64]);
  float ss = v0 * v0 + v1 * v1;
#pragma unroll
  for (int m = 32; m >= 1; m >>= 1) ss += __shfl_xor(ss, m);
  const float rn = rsqrtf(ss * (1.0f / 128.0f) + 1e-6f);
  const float n0 = v0 * rn * (1.0f + w[lane]);
  const float n1 = v1 * rn * (1.0f + w[lane + 64]);
  const float c0 = cosT[(size_t)s * 128 + lane], c1 = cosT[(size_t)s * 128 + lane + 64];
  const float sn0 = sinT[(size_t)s * 128 + lane], sn1 = sinT[(size_t)s * 128 + lane + 64];
  u16* kb = Kpk + (size_t)(b * 4 + g) * (S_LEN * 128);
  kb[kpk_idx(s, lane)]      = f2bf(n0 * c0 - n1 * sn0);
  kb[kpk_idx(s, lane + 64)] = f2bf(n1 * c1 + n0 * sn1);
}

// ---------------- V: QKV bf16 cols 4608.. -> fragment-packed Vpk ----------------
// idx = (s>>5)*4096 + (d>>4)*512 + (d&15)*32 + ((s>>3)&3)*8 + (s&7)
__global__ __launch_bounds__(256) void vtrans(const u16* __restrict__ QKV,
                                              u16* __restrict__ Vpk) {
  __shared__ u16 tile[32][40];
  const int bg = blockIdx.z;                 // b*4+g
  const int s0 = blockIdx.x * 32, d0 = blockIdx.y * 32;
  const int b = bg >> 2, g = bg & 3;
  const int t = threadIdx.x;
  {
    const int sl = t >> 3, dl4 = (t & 7) * 4;
    const ushort4 v = *reinterpret_cast<const ushort4*>(
        QKV + (size_t)(b * S_LEN + s0 + sl) * DQKV + DQG + 512 + g * 128 + d0 + dl4);
    tile[sl][dl4 + 0] = v.x; tile[sl][dl4 + 1] = v.y;
    tile[sl][dl4 + 2] = v.z; tile[sl][dl4 + 3] = v.w;
  }
  __syncthreads();
  {
    const int dl = t >> 3, sl4 = (t & 7) * 4;
    ushort4 o;
    o.x = tile[sl4 + 0][dl]; o.y = tile[sl4 + 1][dl];
    o.z = tile[sl4 + 2][dl]; o.w = tile[sl4 + 3][dl];
    const int d = d0 + dl, s = s0 + sl4;
    const int idx = ((s >> 5) << 12) + ((d >> 4) << 9) + ((d & 15) << 5) +
                    (((s >> 3) & 3) << 3) + (s & 7);
    *reinterpret_cast<ushort4*>(Vpk + (size_t)bg * (S_LEN * 128) + idx) = o;
  }
}

// ---------------- split-K flash attention: partial O/lsum ----------------
// grid (24 jobs, 32 bh); block = 256 thr = 4 waves, each wave 32 q rows.
// Job j (reversed for LPT): j<8 -> qt=j, slot0, kt [0, 2j+2);
// j>=8 -> qt=8+((j-8)>>1); slot=(j-8)&1; slot0 kt [0,qt+1), slot1 [qt+1,2qt+2).
// K/V tiles LDS-staged (linear 16KB DMA from packed layouts), shared by waves.
// Partials additive thanks to no-max softmax.
__global__ __launch_bounds__(256, 3) void attn_part(const u16* __restrict__ Qb,
                                                    const u16* __restrict__ Kpk,
                                                    const u16* __restrict__ Vpk,
                                                    float* __restrict__ O0,
                                                    float* __restrict__ O1,
                                                    float* __restrict__ L0,
                                                    float* __restrict__ L1) {
  __shared__ __align__(16) u16 Ks[8192];       // 64 keys x 128 d, fragment order
  __shared__ __align__(16) u16 Vts[8192];      // 64 keys x 128 d, fragment order
  __shared__ __align__(16) u16 Ps[4][32 * 68]; // per-wave P [q][key]
  const int j = 23 - blockIdx.x, bh = blockIdx.y;
  int qt, slot, kt0, kt1;
  if (j < 8) { qt = j; slot = 0; kt0 = 0; kt1 = 2 * j + 2; }
  else {
    const int i = j - 8; qt = 8 + (i >> 1); slot = i & 1;
    if (slot == 0) { kt0 = 0; kt1 = qt + 1; }
    else           { kt0 = qt + 1; kt1 = 2 * qt + 2; }
  }
  const int tid = threadIdx.x, wv = tid >> 6, lane = tid & 63;
  const int b = bh >> 4, h = bh & 15, g = h >> 2, bg = b * 4 + g;
  const int f = lane & 15, quad = lane >> 4, fq = quad * 8;
  const int lfrag = f * 32 + fq;
  const u16* Kp = Kpk + (size_t)bg * (S_LEN * 128);
  const u16* Vp = Vpk + (size_t)bg * (S_LEN * 128);
  u16* Pw = Ps[wv];
  const int qbase = qt * 128 + wv * 32;

  bf16x8 aq[2][4];
#pragma unroll
  for (int qi = 0; qi < 2; ++qi) {
    const u16* Qp = Qb + ((size_t)bh * S_LEN + qbase + qi * 16) * 128;
#pragma unroll
    for (int c = 0; c < 4; ++c)
      aq[qi][c] = *reinterpret_cast<const bf16x8*>(&Qp[(size_t)f * 128 + c * 32 + fq]);
  }

  floatx4 o[2][8] = {};
  float lsum[2][4] = {};

  for (int kt = kt0; kt < kt1; ++kt) {
    const size_t tb = (size_t)kt * 8192;
    // stage K and V tiles (16 KB each, linear copy; 4 DMA per wave per tensor)
#pragma unroll
    for (int i = 0; i < 4; ++i) {
      const int c = (wv * 4 + i) * 512;
      gload_lds16(Kp + tb + c + lane * 8, &Ks[c]);
      gload_lds16(Vp + tb + c + lane * 8, &Vts[c]);
    }
    __syncthreads();

    const int k0 = kt * 64;
    // ---- QK^T: 4 key-fragments x 4 d-chunks x 2 q-frags ----
#pragma unroll
    for (int n = 0; n < 4; ++n) {
      floatx4 sc0 = {}, sc1 = {};
#pragma unroll
      for (int c = 0; c < 4; ++c) {
        bf16x8 bk = *reinterpret_cast<const bf16x8*>(&Ks[n * 2048 + c * 512 + lfrag]);
        sc0 = __builtin_amdgcn_mfma_f32_16x16x32_bf16(aq[0][c], bk, sc0, 0, 0, 0);
        sc1 = __builtin_amdgcn_mfma_f32_16x16x32_bf16(aq[1][c], bk, sc1, 0, 0, 0);
      }
      const int key = k0 + n * 16 + f;
#pragma unroll
      for (int qi = 0; qi < 2; ++qi) {
        const int qrow0 = qbase + qi * 16 + quad * 4;
        const floatx4 sc = qi ? sc1 : sc0;
#pragma unroll
        for (int r = 0; r < 4; ++r) {
          const float p = (key <= qrow0 + r) ? exp2f(sc[r]) : 0.f;
          lsum[qi][r] += p;
          Pw[(qi * 16 + quad * 4 + r) * 68 + n * 16 + f] = f2bf(p);
        }
      }
    }
    // ---- P @ V: 2 key-fragments x 8 d-chunks x 2 q-frags ----
#pragma unroll
    for (int kf = 0; kf < 2; ++kf) {
      bf16x8 pf0 = *reinterpret_cast<const bf16x8*>(&Pw[f * 68 + kf * 32 + fq]);
      bf16x8 pf1 = *reinterpret_cast<const bf16x8*>(&Pw[(16 + f) * 68 + kf * 32 + fq]);
#pragma unroll
      for (int dt = 0; dt < 8; ++dt) {
        bf16x8 bv = *reinterpret_cast<const bf16x8*>(&Vts[kf * 4096 + dt * 512 + lfrag]);
        o[0][dt] = __builtin_amdgcn_mfma_f32_16x16x32_bf16(pf0, bv, o[0][dt], 0, 0, 0);
        o[1][dt] = __builtin_amdgcn_mfma_f32_16x16x32_bf16(pf1, bv, o[1][dt], 0, 0, 0);
      }
    }
    __syncthreads();
  }

  // reduce lane-partial row sums across the 16 f-lanes of each quad
#pragma unroll
  for (int qi = 0; qi < 2; ++qi)
#pragma unroll
    for (int r = 0; r < 4; ++r) {
#pragma unroll
      for (int mm = 8; mm >= 1; mm >>= 1) lsum[qi][r] += __shfl_xor(lsum[qi][r], mm);
    }

  // write partials
  float* Op = slot ? O1 : O0;
  float* Lp = slot ? L1 : L0;
  const int roff = slot ? 1024 : 0;
  const size_t rows = slot ? 1024 : 2048;
#pragma unroll
  for (int qi = 0; qi < 2; ++qi)
#pragma unroll
    for (int r = 0; r < 4; ++r) {
      const int srow = qbase + qi * 16 + quad * 4 + r;
      float* rp = Op + ((size_t)bh * rows + (srow - roff)) * 128;
#pragma unroll
      for (int dt = 0; dt < 8; ++dt) rp[dt * 16 + f] = o[qi][dt][r];
      if (f == 0) Lp[(size_t)bh * rows + (srow - roff)] = lsum[qi][r];
    }
}

// ---------------- finalize: sum partials, 1/l, sigmoid gate, swizzled ctx ----------------
__global__ __launch_bounds__(256) void attn_fin(const float* __restrict__ O0,
                                                const float* __restrict__ O1,
                                                const float* __restrict__ L0,
                                                const float* __restrict__ L1,
                                                const u16* __restrict__ QKV,
                                                u16* __restrict__ ctxg) {
  const int tid = blockIdx.x * 256 + threadIdx.x;   // 32 bh x 2048 s x 32 d4
  const int d = (tid & 31) * 4;
  const int s = (tid >> 5) & 2047;
  const int bh = tid >> 16;
  const int b = bh >> 4, h = bh & 15;
  float4 o = *reinterpret_cast<const float4*>(O0 + ((size_t)bh * 2048 + s) * 128 + d);
  float l = L0[(size_t)bh * 2048 + s];
  if (s >= 1024) {
    const float4 o1 = *reinterpret_cast<const float4*>(
        O1 + ((size_t)bh * 1024 + s - 1024) * 128 + d);
    o.x += o1.x; o.y += o1.y; o.z += o1.z; o.w += o1.w;
    l += L1[(size_t)bh * 1024 + s - 1024];
  }
  const float inv = 1.0f / l;
  const size_t grow = (size_t)b * S_LEN + s;
  const ushort4 gt = *reinterpret_cast<const ushort4*>(
      QKV + grow * DQKV + h * 256 + 128 + d);
  ushort4 w;
  w.x = f2bf(o.x * inv / (1.0f + __expf(-bf2f(gt.x))));
  w.y = f2bf(o.y * inv / (1.0f + __expf(-bf2f(gt.y))));
  w.z = f2bf(o.z * inv / (1.0f + __expf(-bf2f(gt.z))));
  w.w = f2bf(o.w * inv / (1.0f + __expf(-bf2f(gt.w))));
  *reinterpret_cast<ushort4*>(ctxg + grow * 2048 + swz(h * 128 + d, (int)grow)) = w;
}

extern "C" void kernel_launch(void* const* d_in, const int* in_sizes, int n_in,
                              void* d_out, int out_size, void* d_ws, size_t ws_size,
                              hipStream_t stream) {
  const float* x    = (const float*)d_in[0];
  const float* Wq   = (const float*)d_in[1];
  const float* Wk   = (const float*)d_in[2];
  const float* Wv   = (const float*)d_in[3];
  const float* Wo   = (const float*)d_in[4];
  const float* qnw  = (const float*)d_in[5];
  const float* knw  = (const float*)d_in[6];
  const float* cosT = (const float*)d_in[7];
  const float* sinT = (const float*)d_in[8];
  // d_in[9] = mask (unused; causality computed analytically)

  char* p = (char*)d_ws;
  // Opart region overlaps xb+WqkvT (dead after the QKV GEMM) + spill space
  float* O0 = (float*)p;                         // 32*2048*128 fp32 = 33.55 MB
  float* O1 = O0 + (size_t)32 * 2048 * 128;      // 32*1024*128 fp32 = 16.78 MB
  float* L0 = O1 + (size_t)32 * 1024 * 128;      // 0.26 MB
  float* L1 = L0 + (size_t)32 * 2048;            // 0.13 MB
  const size_t opart_bytes = ((size_t)32 * 2048 * 128 + (size_t)32 * 1024 * 128 +
                              (size_t)32 * 2048 + (size_t)32 * 1024) * 4;

  u16* xb    = (u16*)p;  p += (size_t)NROWS * DIN * 2;        // 16.78 MB
  u16* WqkvT = (u16*)p;  p += (size_t)DQKV * DIN * 2;         // 20.97 MB
  {
    const size_t used = (size_t)NROWS * DIN * 2 + (size_t)DQKV * DIN * 2;
    if (opart_bytes > used) p = (char*)d_ws + opart_bytes;    // spill past the reuse zone
  }
  u16* WoT   = (u16*)p;  p += (size_t)2048 * 2048 * 2;        // 8.39 MB
  u16* QKVb  = (u16*)p;  p += (size_t)NROWS * DQKV * 2;       // 41.94 MB
  u16* Qbf   = (u16*)p;  p += (size_t)2 * 16 * S_LEN * 128 * 2;
  u16* Kpk   = (u16*)p;  p += (size_t)2 * 4 * S_LEN * 128 * 2;
  u16* Vpk   = (u16*)p;  p += (size_t)2 * 4 * S_LEN * 128 * 2;
  u16* ctxg  = (u16*)p;  p += (size_t)NROWS * 2048 * 2;

  cvt_x<<<8192, 256, 0, stream>>>(x, xb);
  tcvt<<<dim3(128, 64), 256, 0, stream>>>(Wq, WqkvT, 2048, 4096, 2048);
  tcvt<<<dim3(16, 64), 256, 0, stream>>>(Wk, WqkvT + (size_t)4096 * 2048, 2048, 512, 2048);
  tcvt<<<dim3(16, 64), 256, 0, stream>>>(Wv, WqkvT + (size_t)4608 * 2048, 2048, 512, 2048);
  tcvt<<<dim3(64, 64), 256, 0, stream>>>(Wo, WoT, 2048, 2048, 2048);

  gemm_bt<true><<<dim3(40, 32), 256, 0, stream>>>(xb, WqkvT, QKVb, NROWS, DQKV, DIN);

  qnorm_rope<<<16384, 256, 0, stream>>>(QKVb, qnw, cosT, sinT, Qbf);
  knorm_rope<<<4096, 256, 0, stream>>>(QKVb, knw, cosT, sinT, Kpk);
  vtrans<<<dim3(64, 4, 8), 256, 0, stream>>>(QKVb, Vpk);

  attn_part<<<dim3(24, 32), 256, 0, stream>>>(Qbf, Kpk, Vpk, O0, O1, L0, L1);
  attn_fin<<<8192, 256, 0, stream>>>(O0, O1, L0, L1, QKVb, ctxg);

  gemm_bt<false><<<dim3(16, 32), 256, 0, stream>>>(ctxg, WoT, (float*)d_out, NROWS, 2048, 2048);
}